// Round 1
// baseline (284.861 us; speedup 1.0000x reference)
//
#include <hip/hip_runtime.h>
#include <hip/hip_bf16.h>
#include <math.h>

#define NT 16384
#define DIM 2048
#define NE 64
#define TK 8

// ---------------- Kernel A: router scalar chain + bias, zero batch-load accum ----------------
__global__ __launch_bounds__(64) void scalars_kernel(const float* __restrict__ expert_loads,
                                                     const float* __restrict__ bias_strength,
                                                     float* __restrict__ ws_bias,
                                                     float* __restrict__ ws_batch,
                                                     float* __restrict__ out_bias_strength) {
    int e = threadIdx.x;
    float load = expert_loads[e];
    float s = load;
    #pragma unroll
    for (int off = 32; off >= 1; off >>= 1) s += __shfl_xor(s, off, 64);
    s = fmaxf(s, 1e-8f);
    float q = load / s;
    const float t = 1.0f / 64.0f;
    float kt = t * (logf(t) - logf(fmaxf(q, 1e-8f)));
    float kl = kt;
    #pragma unroll
    for (int off = 32; off >= 1; off >>= 1) kl += __shfl_xor(kl, off, 64);
    float as = 1.0f / (1.0f + expf(-10.0f * kl));
    float nbs = 0.9f * bias_strength[0] + 0.1f * as;
    float bias = tanhf((q - t) * 64.0f) * nbs;
    ws_bias[e] = bias;
    ws_batch[e] = 0.0f;
    if (e == 0) out_bias_strength[0] = nbs;
}

// ---------------- Kernel B: GEMM + noise + bias + top-8 + softmax + load scatter ----------------
__global__ __launch_bounds__(256) void router_main(const float* __restrict__ x,
                                                   const float* __restrict__ w,
                                                   const float* __restrict__ noise,
                                                   const float* __restrict__ ws_bias,
                                                   float* __restrict__ ws_batch,
                                                   float* __restrict__ out) {
    // Row stride 68 floats = 272 B: 16B-aligned rows (b128 legal) and, with the
    // stride-16 token/expert->thread mapping below, compute-phase b128 reads are
    // only 2-way bank aliased (free). Stride-4 mapping would be 8-way (~2.9x).
    __shared__ float xs[64][68];
    __shared__ float wsh[64][68];
    __shared__ float lg[64][65];   // logits for top-k phase (2-way max on scan)
    __shared__ float loads_sh[64];

    const int tid = threadIdx.x;
    const int token0 = blockIdx.x * 64;
    if (tid < 64) loads_sh[tid] = 0.0f;

    const int tm = tid & 15;   // token lane: handles tokens {tm, tm+16, tm+32, tm+48}
    const int te = tid >> 4;   // expert lane: handles experts {te, te+16, te+32, te+48}

    float acc[4][4];
    #pragma unroll
    for (int i = 0; i < 4; i++)
        #pragma unroll
        for (int j = 0; j < 4; j++) acc[i][j] = 0.0f;

    for (int k0 = 0; k0 < DIM; k0 += 64) {
        __syncthreads();   // also covers loads_sh zero-init visibility on first iter
        #pragma unroll
        for (int i = 0; i < 4; i++) {
            int f = tid + 256 * i;        // 0..1023 float4 slots
            int t = f >> 4;               // 0..63 row
            int ks = (f & 15) << 2;       // 0..60 k-offset
            float4 xv = *(const float4*)(x + (size_t)(token0 + t) * DIM + k0 + ks);
            *(float4*)&xs[t][ks] = xv;
            float4 wv = *(const float4*)(w + (size_t)t * DIM + k0 + ks);
            *(float4*)&wsh[t][ks] = wv;
        }
        __syncthreads();
        #pragma unroll
        for (int kk = 0; kk < 64; kk += 4) {
            float4 xa[4], wa[4];
            #pragma unroll
            for (int i = 0; i < 4; i++) xa[i] = *(const float4*)&xs[tm + 16 * i][kk];
            #pragma unroll
            for (int j = 0; j < 4; j++) wa[j] = *(const float4*)&wsh[te + 16 * j][kk];
            #pragma unroll
            for (int i = 0; i < 4; i++)
                #pragma unroll
                for (int j = 0; j < 4; j++) {
                    acc[i][j] = fmaf(xa[i].x, wa[j].x, acc[i][j]);
                    acc[i][j] = fmaf(xa[i].y, wa[j].y, acc[i][j]);
                    acc[i][j] = fmaf(xa[i].z, wa[j].z, acc[i][j]);
                    acc[i][j] = fmaf(xa[i].w, wa[j].w, acc[i][j]);
                }
        }
    }

    // Epilogue: logits = acc + noise*0.01 - bias -> LDS
    #pragma unroll
    for (int i = 0; i < 4; i++) {
        int t = tm + 16 * i;
        #pragma unroll
        for (int j = 0; j < 4; j++) {
            int e = te + 16 * j;
            float val = acc[i][j] + noise[(size_t)(token0 + t) * NE + e] * 0.01f - ws_bias[e];
            lg[t][e] = val;
        }
    }
    __syncthreads();

    // Top-8 (jax.lax.top_k tie semantics: lower index first -> strict '>' keeps
    // earlier-scanned/lower index ahead on equality) + softmax over selected.
    if (tid < 64) {
        int t = tid;
        float tv[TK]; int ti_[TK];
        #pragma unroll
        for (int j = 0; j < TK; j++) { tv[j] = -INFINITY; ti_[j] = 0; }
        for (int e = 0; e < NE; e++) {
            float v = lg[t][e]; int id = e;
            #pragma unroll
            for (int j = 0; j < TK; j++) {
                bool gt = v > tv[j];
                float nv = gt ? v : tv[j];
                int   ni = gt ? id : ti_[j];
                float ov = gt ? tv[j] : v;
                int   oi = gt ? ti_[j] : id;
                tv[j] = nv; ti_[j] = ni; v = ov; id = oi;
            }
        }
        float m = tv[0];
        float wv[TK];
        float ssum = 0.0f;
        #pragma unroll
        for (int j = 0; j < TK; j++) { wv[j] = expf(tv[j] - m); ssum += wv[j]; }
        float inv = 1.0f / ssum;
        size_t gt_ = (size_t)(token0 + t);
        #pragma unroll
        for (int j = 0; j < TK; j++) {
            float wgt = wv[j] * inv;
            out[gt_ * TK + j] = (float)ti_[j];                     // indices (as f32)
            out[(size_t)NT * TK + gt_ * TK + j] = wgt;             // gate weights
            atomicAdd(&loads_sh[ti_[j]], wgt);
        }
    }
    __syncthreads();
    if (tid < 64) atomicAdd(&ws_batch[tid], loads_sh[tid]);
}

// ---------------- Kernel C: EMA load update ----------------
__global__ __launch_bounds__(64) void finalize_kernel(const float* __restrict__ expert_loads,
                                                      const float* __restrict__ ws_batch,
                                                      float* __restrict__ out_loads) {
    int e = threadIdx.x;
    out_loads[e] = 0.999f * expert_loads[e] + 0.001f * (ws_batch[e] / (float)NT);
}

extern "C" void kernel_launch(void* const* d_in, const int* in_sizes, int n_in,
                              void* d_out, int out_size, void* d_ws, size_t ws_size,
                              hipStream_t stream) {
    const float* x      = (const float*)d_in[0];  // [16384, 2048]
    const float* rw     = (const float*)d_in[1];  // [64, 2048]
    const float* loads  = (const float*)d_in[2];  // [64]
    const float* bs     = (const float*)d_in[3];  // [1]
    const float* noise  = (const float*)d_in[4];  // [16384, 64]
    float* out = (float*)d_out;                   // [131072 idx | 131072 w | 64 loads | 1 bias]
    float* ws  = (float*)d_ws;
    float* ws_bias  = ws;
    float* ws_batch = ws + 64;

    scalars_kernel<<<1, 64, 0, stream>>>(loads, bs, ws_bias, ws_batch,
                                         out + (size_t)NT * TK * 2 + NE);
    router_main<<<NT / 64, 256, 0, stream>>>(x, rw, noise, ws_bias, ws_batch, out);
    finalize_kernel<<<1, 64, 0, stream>>>(loads, ws_batch, out + (size_t)NT * TK * 2);
}

// Round 2
// 222.023 us; speedup vs baseline: 1.2830x; 1.2830x over previous
//
#include <hip/hip_runtime.h>
#include <hip/hip_bf16.h>
#include <math.h>

#define NT 16384
#define DIM 2048
#define NE 64
#define TK 8

typedef _Float16 f16_t;
typedef _Float16 half8 __attribute__((ext_vector_type(8)));
typedef float floatx16 __attribute__((ext_vector_type(16)));

// ---------------- Prep: W fp32 -> f16 hi/lo in 32x32x16 B-fragment order; block 64 = scalar chain ----------------
// Fragment layout assumption (32x32x16): B[n = lane&31][k = 8*(lane>>5) + j], j=0..7 -> one 16B half8/lane.
__global__ __launch_bounds__(256) void prep_kernel(const float* __restrict__ w,
                                                   const float* __restrict__ expert_loads,
                                                   const float* __restrict__ bias_strength,
                                                   float* __restrict__ ws_bias,
                                                   float* __restrict__ ws_batch,
                                                   f16_t* __restrict__ whi,
                                                   f16_t* __restrict__ wlo,
                                                   float* __restrict__ out_bias_strength) {
    if (blockIdx.x == 64) {
        int e = threadIdx.x;
        if (e < 64) {
            float load = expert_loads[e];
            float s = load;
            #pragma unroll
            for (int off = 32; off >= 1; off >>= 1) s += __shfl_xor(s, off, 64);
            s = fmaxf(s, 1e-8f);
            float q = load / s;
            const float t = 1.0f / 64.0f;
            float kl = t * (logf(t) - logf(fmaxf(q, 1e-8f)));
            #pragma unroll
            for (int off = 32; off >= 1; off >>= 1) kl += __shfl_xor(kl, off, 64);
            float as = 1.0f / (1.0f + expf(-10.0f * kl));
            float nbs = 0.9f * bias_strength[0] + 0.1f * as;
            ws_bias[e] = tanhf((q - t) * 64.0f) * nbs;
            ws_batch[e] = 0.0f;
            if (e == 0) out_bias_strength[0] = nbs;
        }
        return;
    }
    int idx = blockIdx.x * 256 + threadIdx.x;   // 0..16383 = (c, tile, lane)
    int lane = idx & 63;
    int tile = (idx >> 6) & 1;
    int c    = idx >> 7;                         // k-chunk of 16
    int n = tile * 32 + (lane & 31);
    int k = c * 16 + (lane >> 5) * 8;
    const float* src = w + (size_t)n * DIM + k;
    float4 a = *(const float4*)src;
    float4 b = *(const float4*)(src + 4);
    float v[8] = {a.x, a.y, a.z, a.w, b.x, b.y, b.z, b.w};
    half8 h, l;
    #pragma unroll
    for (int j = 0; j < 8; ++j) {
        f16_t hh = (f16_t)v[j];
        h[j] = hh;
        l[j] = (f16_t)(v[j] - (float)hh);
    }
    *(half8*)(whi + (size_t)idx * 8) = h;
    *(half8*)(wlo + (size_t)idx * 8) = l;
}

// ---------------- Main: split-f16 MFMA GEMM + noise + bias + top-8 + softmax + load scatter ----------------
// Block: 256 thr = 4 waves. Block tile: 32 tokens x 64 experts. Split-K: wave w owns K range [w*512,(w+1)*512).
// No LDS / no barriers in the K-loop: A-frags global->reg (L1-paired granules), B-frags coalesced from L2.
__global__ __launch_bounds__(256) void router_main(const float* __restrict__ x,
                                                   const f16_t* __restrict__ whi,
                                                   const f16_t* __restrict__ wlo,
                                                   const float* __restrict__ noise,
                                                   const float* __restrict__ ws_bias,
                                                   float* __restrict__ ws_batch,
                                                   float* __restrict__ out) {
    __shared__ float part[4][32][72];   // per-wave split-K partials; stride 72 breaks pow2 banks
    __shared__ float bias_sh[64];
    __shared__ float loads_sh[64];

    const int tid = threadIdx.x;
    const int wv  = tid >> 6;       // wave id = K partition
    const int L   = tid & 63;
    const int r   = L & 31;         // token row within tile (A-frag m)
    const int kh  = L >> 5;         // k-half within 16-chunk
    const int token0 = blockIdx.x * 32;

    if (tid < 64) { bias_sh[tid] = ws_bias[tid]; loads_sh[tid] = 0.0f; }

    const float* xp = x + (size_t)(token0 + r) * DIM + wv * 512 + kh * 8;
    const half8* whi8 = (const half8*)whi;
    const half8* wlo8 = (const half8*)wlo;

    floatx16 acc0, acc1;
    #pragma unroll
    for (int i = 0; i < 16; ++i) { acc0[i] = 0.0f; acc1[i] = 0.0f; }

    #pragma unroll 4
    for (int c = 0; c < 32; ++c) {
        float4 a0 = *(const float4*)(xp + c * 16);
        float4 a1 = *(const float4*)(xp + c * 16 + 4);
        int base = ((wv * 32 + c) * 2) * 64 + L;
        half8 b0h = whi8[base];
        half8 b1h = whi8[base + 64];
        half8 b0l = wlo8[base];
        half8 b1l = wlo8[base + 64];
        float xv[8] = {a0.x, a0.y, a0.z, a0.w, a1.x, a1.y, a1.z, a1.w};
        half8 ah, al;
        #pragma unroll
        for (int j = 0; j < 8; ++j) {
            f16_t h = (f16_t)xv[j];
            ah[j] = h;
            al[j] = (f16_t)(xv[j] - (float)h);
        }
        acc0 = __builtin_amdgcn_mfma_f32_32x32x16_f16(ah, b0h, acc0, 0, 0, 0);
        acc1 = __builtin_amdgcn_mfma_f32_32x32x16_f16(ah, b1h, acc1, 0, 0, 0);
        acc0 = __builtin_amdgcn_mfma_f32_32x32x16_f16(al, b0h, acc0, 0, 0, 0);
        acc1 = __builtin_amdgcn_mfma_f32_32x32x16_f16(al, b1h, acc1, 0, 0, 0);
        acc0 = __builtin_amdgcn_mfma_f32_32x32x16_f16(ah, b0l, acc0, 0, 0, 0);
        acc1 = __builtin_amdgcn_mfma_f32_32x32x16_f16(ah, b1l, acc1, 0, 0, 0);
    }

    // C/D layout (verified m74/m101): col = lane&31, row = (reg&3) + 8*(reg>>2) + 4*(lane>>5)
    #pragma unroll
    for (int reg = 0; reg < 16; ++reg) {
        int row = (reg & 3) + 8 * (reg >> 2) + 4 * kh;
        part[wv][row][r]      = acc0[reg];
        part[wv][row][32 + r] = acc1[reg];
    }
    __syncthreads();

    // Split-K reduce + noise + bias -> final logits in part[0][t][e]
    #pragma unroll
    for (int p = 0; p < 8; ++p) {
        int o = tid + p * 256;          // 0..2047
        int t = o >> 6, e = o & 63;
        float s = part[0][t][e] + part[1][t][e] + part[2][t][e] + part[3][t][e];
        s += noise[(size_t)(token0 + t) * NE + e] * 0.01f - bias_sh[e];
        part[0][t][e] = s;
    }
    __syncthreads();

    // Top-8 (strict '>' keeps lower index on ties, matching jax.lax.top_k) + softmax + LDS load scatter
    if (tid < 32) {
        int t = tid;
        float tv[TK]; int ti_[TK];
        #pragma unroll
        for (int j = 0; j < TK; ++j) { tv[j] = -INFINITY; ti_[j] = 0; }
        for (int e = 0; e < NE; ++e) {
            float v = part[0][t][e]; int id = e;
            #pragma unroll
            for (int j = 0; j < TK; ++j) {
                bool gt = v > tv[j];
                float nv = gt ? v : tv[j];
                int   ni = gt ? id : ti_[j];
                float ov = gt ? tv[j] : v;
                int   oi = gt ? ti_[j] : id;
                tv[j] = nv; ti_[j] = ni; v = ov; id = oi;
            }
        }
        float m = tv[0], ssum = 0.0f, wvv[TK];
        #pragma unroll
        for (int j = 0; j < TK; ++j) { wvv[j] = expf(tv[j] - m); ssum += wvv[j]; }
        float inv = 1.0f / ssum;
        size_t gt_ = (size_t)(token0 + t);
        #pragma unroll
        for (int j = 0; j < TK; ++j) {
            float wgt = wvv[j] * inv;
            out[gt_ * TK + j] = (float)ti_[j];
            out[(size_t)NT * TK + gt_ * TK + j] = wgt;
            atomicAdd(&loads_sh[ti_[j]], wgt);
        }
    }
    __syncthreads();
    if (tid < 64) atomicAdd(&ws_batch[tid], loads_sh[tid]);
}

// ---------------- EMA load update ----------------
__global__ __launch_bounds__(64) void finalize_kernel(const float* __restrict__ expert_loads,
                                                      const float* __restrict__ ws_batch,
                                                      float* __restrict__ out_loads) {
    int e = threadIdx.x;
    out_loads[e] = 0.999f * expert_loads[e] + 0.001f * (ws_batch[e] / (float)NT);
}

extern "C" void kernel_launch(void* const* d_in, const int* in_sizes, int n_in,
                              void* d_out, int out_size, void* d_ws, size_t ws_size,
                              hipStream_t stream) {
    const float* x     = (const float*)d_in[0];  // [16384, 2048]
    const float* rw    = (const float*)d_in[1];  // [64, 2048]
    const float* loads = (const float*)d_in[2];  // [64]
    const float* bs    = (const float*)d_in[3];  // [1]
    const float* noise = (const float*)d_in[4];  // [16384, 64]
    float* out = (float*)d_out;                  // [131072 idx | 131072 w | 64 loads | 1 bias]
    float* ws  = (float*)d_ws;
    float* ws_bias  = ws;
    float* ws_batch = ws + 64;
    f16_t* whi = (f16_t*)(ws + 128);             // 16384 frags x 8 halves = 256 KB
    f16_t* wlo = whi + (size_t)16384 * 8;        // another 256 KB

    prep_kernel<<<65, 256, 0, stream>>>(rw, loads, bs, ws_bias, ws_batch, whi, wlo,
                                        out + (size_t)NT * TK * 2 + NE);
    router_main<<<NT / 32, 256, 0, stream>>>(x, whi, wlo, noise, ws_bias, ws_batch, out);
    finalize_kernel<<<1, 64, 0, stream>>>(loads, ws_batch, out + (size_t)NT * TK * 2);
}

// Round 3
// 221.393 us; speedup vs baseline: 1.2867x; 1.0028x over previous
//
#include <hip/hip_runtime.h>
#include <hip/hip_bf16.h>
#include <math.h>

#define NT 16384
#define DIM 2048
#define NE 64
#define TK 8

typedef _Float16 f16_t;
typedef _Float16 half8 __attribute__((ext_vector_type(8)));
typedef float floatx16 __attribute__((ext_vector_type(16)));

typedef __attribute__((address_space(3))) unsigned int  lds_u32;
typedef __attribute__((address_space(1))) const unsigned int gbl_u32;

// ---------------- Prep: W fp32 -> f16 hi/lo in 32x32x16 B-fragment order; block 64 = scalar chain ----------------
// B-frag layout (verified R2-pass): lane holds B[n=lane&31][k=8*(lane>>5)+j], one 16B half8 per frag.
__global__ __launch_bounds__(256) void prep_kernel(const float* __restrict__ w,
                                                   const float* __restrict__ expert_loads,
                                                   const float* __restrict__ bias_strength,
                                                   float* __restrict__ ws_bias,
                                                   float* __restrict__ ws_batch,
                                                   f16_t* __restrict__ whi,
                                                   f16_t* __restrict__ wlo,
                                                   float* __restrict__ out_bias_strength) {
    if (blockIdx.x == 64) {
        int e = threadIdx.x;
        if (e < 64) {
            float load = expert_loads[e];
            float s = load;
            #pragma unroll
            for (int off = 32; off >= 1; off >>= 1) s += __shfl_xor(s, off, 64);
            s = fmaxf(s, 1e-8f);
            float q = load / s;
            const float t = 1.0f / 64.0f;
            float kl = t * (logf(t) - logf(fmaxf(q, 1e-8f)));
            #pragma unroll
            for (int off = 32; off >= 1; off >>= 1) kl += __shfl_xor(kl, off, 64);
            float as = 1.0f / (1.0f + expf(-10.0f * kl));
            float nbs = 0.9f * bias_strength[0] + 0.1f * as;
            ws_bias[e] = tanhf((q - t) * 64.0f) * nbs;
            ws_batch[e] = 0.0f;
            if (e == 0) out_bias_strength[0] = nbs;
        }
        return;
    }
    int idx = blockIdx.x * 256 + threadIdx.x;   // (c16, tile, lane)
    int lane = idx & 63;
    int tile = (idx >> 6) & 1;
    int c    = idx >> 7;
    int n = tile * 32 + (lane & 31);
    int k = c * 16 + (lane >> 5) * 8;
    const float* src = w + (size_t)n * DIM + k;
    float4 a = *(const float4*)src;
    float4 b = *(const float4*)(src + 4);
    float v[8] = {a.x, a.y, a.z, a.w, b.x, b.y, b.z, b.w};
    half8 h, l;
    #pragma unroll
    for (int j = 0; j < 8; ++j) {
        f16_t hh = (f16_t)v[j];
        h[j] = hh;
        l[j] = (f16_t)(v[j] - (float)hh);
    }
    *(half8*)(whi + (size_t)idx * 8) = h;
    *(half8*)(wlo + (size_t)idx * 8) = l;
}

// ---------------- Main: LDS-staged split-f16 MFMA GEMM + noise + bias + top-8 + softmax ----------------
// 512 thr = 8 waves = split-K x8 (256 floats each). Tile 32 tokens x 64 experts. Grid 512 = 2 blocks/CU.
// K-loop has NO barriers: each wave stages its own x-chunk via global_load_lds into a wave-private
// buffer (4-row groups of 1KB + 16B pad), waits vmcnt(0), reads frags, MFMAs. 4 waves/SIMD hide latency.
__global__ __launch_bounds__(512, 4) void router_main(const float* __restrict__ x,
                                                      const f16_t* __restrict__ whi,
                                                      const f16_t* __restrict__ wlo,
                                                      const float* __restrict__ noise,
                                                      const float* __restrict__ ws_bias,
                                                      float* __restrict__ ws_batch,
                                                      float* __restrict__ out) {
    // 69,632 B: K-loop staging (8 waves x 8,320 B) overlaid with part[8][32][68] f32 afterwards
    __shared__ float smem[17408];
    __shared__ float bias_sh[64];
    __shared__ float loads_sh[64];

    const int tid = threadIdx.x;
    const int wv  = tid >> 6;        // 0..7: K partition (k range [wv*256, wv*256+256))
    const int L   = tid & 63;
    const int r   = L & 31;          // token row within tile (A-frag m / C col per layout)
    const int kh  = L >> 5;
    const int token0 = blockIdx.x * 32;

    if (tid < 64) { bias_sh[tid] = ws_bias[tid]; loads_sh[tid] = 0.0f; }

    char* mybuf = (char*)smem + wv * 8320;   // 8 groups x (1024 + 16 pad)
    const half8* whi8 = (const half8*)whi;
    const half8* wlo8 = (const half8*)wlo;

    floatx16 acc0, acc1;
    #pragma unroll
    for (int i = 0; i < 16; ++i) { acc0[i] = 0.0f; acc1[i] = 0.0f; }

    // staging addresses: instr g stages rows 4g..4g+3, 256B (one BK=64 chunk) each
    const int srow = L >> 4;                 // row within group
    const int sb   = (L & 15) * 16;          // byte within row-chunk
    const float* xbase = x + (size_t)token0 * DIM + wv * 256;

    const int gfrag = r >> 2;                // frag-read group
    const int mfrag = r & 3;

    for (int ch = 0; ch < 4; ++ch) {
        // prior chunk's ds_reads must drain before DMA overwrites the buffer
        asm volatile("s_waitcnt lgkmcnt(0)" ::: "memory");
        #pragma unroll
        for (int g = 0; g < 8; ++g) {
            const char* gp = (const char*)(xbase + (size_t)(4 * g + srow) * DIM + ch * 64) + sb;
            __builtin_amdgcn_global_load_lds((gbl_u32*)gp, (lds_u32*)(mybuf + g * 1040), 16, 0, 0);
        }
        asm volatile("s_waitcnt vmcnt(0)" ::: "memory");   // staged data visible in LDS

        #pragma unroll
        for (int cc = 0; cc < 4; ++cc) {
            const int c16 = wv * 16 + ch * 4 + cc;         // global 16-k chunk index
            const float* fp = (const float*)(mybuf + gfrag * 1040 + mfrag * 256 + cc * 64 + kh * 32);
            float4 a0 = *(const float4*)fp;
            float4 a1 = *(const float4*)(fp + 4);
            float xv[8] = {a0.x, a0.y, a0.z, a0.w, a1.x, a1.y, a1.z, a1.w};
            half8 ah, al;
            #pragma unroll
            for (int j = 0; j < 8; ++j) {
                f16_t h = (f16_t)xv[j];
                ah[j] = h;
                al[j] = (f16_t)(xv[j] - (float)h);
            }
            const int bidx = (c16 * 2) * 64 + L;
            half8 b0h = whi8[bidx];
            half8 b1h = whi8[bidx + 64];
            half8 b0l = wlo8[bidx];
            half8 b1l = wlo8[bidx + 64];
            acc0 = __builtin_amdgcn_mfma_f32_32x32x16_f16(ah, b0h, acc0, 0, 0, 0);
            acc1 = __builtin_amdgcn_mfma_f32_32x32x16_f16(ah, b1h, acc1, 0, 0, 0);
            acc0 = __builtin_amdgcn_mfma_f32_32x32x16_f16(al, b0h, acc0, 0, 0, 0);
            acc1 = __builtin_amdgcn_mfma_f32_32x32x16_f16(al, b1h, acc1, 0, 0, 0);
            acc0 = __builtin_amdgcn_mfma_f32_32x32x16_f16(ah, b0l, acc0, 0, 0, 0);
            acc1 = __builtin_amdgcn_mfma_f32_32x32x16_f16(ah, b1l, acc1, 0, 0, 0);
        }
    }

    __syncthreads();   // all waves done with staging region; reuse as part[]

    // C/D layout (verified m74/m101 + R2 pass): col = lane&31 (= token r? no: = N dim), here
    // A rows = tokens (col of C = lane&31 indexes N = experts? no). Matches R2 exactly:
    // part[wv][tokenRow][expertCol]: row=(reg&3)+8*(reg>>2)+4*kh (token), col=r.. experts from B halves.
    #pragma unroll
    for (int reg = 0; reg < 16; ++reg) {
        int row = (reg & 3) + 8 * (reg >> 2) + 4 * kh;
        smem[wv * 2176 + row * 68 + r]      = acc0[reg];
        smem[wv * 2176 + row * 68 + 32 + r] = acc1[reg];
    }
    __syncthreads();

    // Split-K reduce + noise + bias -> final logits into part[0]
    #pragma unroll
    for (int p = 0; p < 4; ++p) {
        int o = tid + p * 512;               // 0..2047
        int t = o >> 6, e = o & 63;
        float s = 0.0f;
        #pragma unroll
        for (int q = 0; q < 8; ++q) s += smem[q * 2176 + t * 68 + e];
        s += noise[(size_t)(token0 + t) * NE + e] * 0.01f - bias_sh[e];
        smem[t * 68 + e] = s;                // own (t,e) slot only; no cross-thread hazard
    }
    __syncthreads();

    // Top-8 (strict '>' keeps lower index on ties, matching jax.lax.top_k) + softmax + load scatter
    if (tid < 32) {
        int t = tid;
        float tv[TK]; int ti_[TK];
        #pragma unroll
        for (int j = 0; j < TK; ++j) { tv[j] = -INFINITY; ti_[j] = 0; }
        for (int e = 0; e < NE; ++e) {
            float v = smem[t * 68 + e]; int id = e;
            #pragma unroll
            for (int j = 0; j < TK; ++j) {
                bool gt = v > tv[j];
                float nv = gt ? v : tv[j];
                int   ni = gt ? id : ti_[j];
                float ov = gt ? tv[j] : v;
                int   oi = gt ? ti_[j] : id;
                tv[j] = nv; ti_[j] = ni; v = ov; id = oi;
            }
        }
        float m = tv[0], ssum = 0.0f, wvv[TK];
        #pragma unroll
        for (int j = 0; j < TK; ++j) { wvv[j] = expf(tv[j] - m); ssum += wvv[j]; }
        float inv = 1.0f / ssum;
        size_t gt_ = (size_t)(token0 + t);
        #pragma unroll
        for (int j = 0; j < TK; ++j) {
            float wgt = wvv[j] * inv;
            out[gt_ * TK + j] = (float)ti_[j];
            out[(size_t)NT * TK + gt_ * TK + j] = wgt;
            atomicAdd(&loads_sh[ti_[j]], wgt);
        }
    }
    __syncthreads();
    if (tid < 64) atomicAdd(&ws_batch[tid], loads_sh[tid]);
}

// ---------------- EMA load update ----------------
__global__ __launch_bounds__(64) void finalize_kernel(const float* __restrict__ expert_loads,
                                                      const float* __restrict__ ws_batch,
                                                      float* __restrict__ out_loads) {
    int e = threadIdx.x;
    out_loads[e] = 0.999f * expert_loads[e] + 0.001f * (ws_batch[e] / (float)NT);
}

extern "C" void kernel_launch(void* const* d_in, const int* in_sizes, int n_in,
                              void* d_out, int out_size, void* d_ws, size_t ws_size,
                              hipStream_t stream) {
    const float* x     = (const float*)d_in[0];  // [16384, 2048]
    const float* rw    = (const float*)d_in[1];  // [64, 2048]
    const float* loads = (const float*)d_in[2];  // [64]
    const float* bs    = (const float*)d_in[3];  // [1]
    const float* noise = (const float*)d_in[4];  // [16384, 64]
    float* out = (float*)d_out;                  // [131072 idx | 131072 w | 64 loads | 1 bias]
    float* ws  = (float*)d_ws;
    float* ws_bias  = ws;
    float* ws_batch = ws + 64;
    f16_t* whi = (f16_t*)(ws + 128);             // 16384 frags x 8 halves = 256 KB
    f16_t* wlo = whi + (size_t)16384 * 8;        // another 256 KB

    prep_kernel<<<65, 256, 0, stream>>>(rw, loads, bs, ws_bias, ws_batch, whi, wlo,
                                        out + (size_t)NT * TK * 2 + NE);
    router_main<<<NT / 32, 512, 0, stream>>>(x, whi, wlo, noise, ws_bias, ws_batch, out);
    finalize_kernel<<<1, 64, 0, stream>>>(loads, ws_batch, out + (size_t)NT * TK * 2);
}

// Round 4
// 218.712 us; speedup vs baseline: 1.3024x; 1.0123x over previous
//
#include <hip/hip_runtime.h>
#include <hip/hip_bf16.h>
#include <math.h>

#define NT 16384
#define DIM 2048
#define NE 64
#define TK 8

typedef _Float16 f16_t;
typedef _Float16 half8 __attribute__((ext_vector_type(8)));
typedef float floatx16 __attribute__((ext_vector_type(16)));

union H8U4 { uint4 u; half8 h; };

// ---------------- Prep: W fp32 -> f16 hi/lo in 32x32x16 B-fragment order; block 64 = scalar chain ----------------
// B-frag layout (verified R2/R3 pass): lane holds B[n=lane&31][k=8*(lane>>5)+j], one 16B half8 per frag.
__global__ __launch_bounds__(256) void prep_kernel(const float* __restrict__ w,
                                                   const float* __restrict__ expert_loads,
                                                   const float* __restrict__ bias_strength,
                                                   float* __restrict__ ws_bias,
                                                   float* __restrict__ ws_batch,
                                                   f16_t* __restrict__ whi,
                                                   f16_t* __restrict__ wlo,
                                                   float* __restrict__ out_bias_strength) {
    if (blockIdx.x == 64) {
        int e = threadIdx.x;
        if (e < 64) {
            float load = expert_loads[e];
            float s = load;
            #pragma unroll
            for (int off = 32; off >= 1; off >>= 1) s += __shfl_xor(s, off, 64);
            s = fmaxf(s, 1e-8f);
            float q = load / s;
            const float t = 1.0f / 64.0f;
            float kl = t * (logf(t) - logf(fmaxf(q, 1e-8f)));
            #pragma unroll
            for (int off = 32; off >= 1; off >>= 1) kl += __shfl_xor(kl, off, 64);
            float as = 1.0f / (1.0f + expf(-10.0f * kl));
            float nbs = 0.9f * bias_strength[0] + 0.1f * as;
            ws_bias[e] = tanhf((q - t) * 64.0f) * nbs;
            ws_batch[e] = 0.0f;
            if (e == 0) out_bias_strength[0] = nbs;
        }
        return;
    }
    int idx = blockIdx.x * 256 + threadIdx.x;   // (c16, tile, lane)
    int lane = idx & 63;
    int tile = (idx >> 6) & 1;
    int c    = idx >> 7;
    int n = tile * 32 + (lane & 31);
    int k = c * 16 + (lane >> 5) * 8;
    const float* src = w + (size_t)n * DIM + k;
    float4 a = *(const float4*)src;
    float4 b = *(const float4*)(src + 4);
    float v[8] = {a.x, a.y, a.z, a.w, b.x, b.y, b.z, b.w};
    half8 h, l;
    #pragma unroll
    for (int j = 0; j < 8; ++j) {
        f16_t hh = (f16_t)v[j];
        h[j] = hh;
        l[j] = (f16_t)(v[j] - (float)hh);
    }
    *(half8*)(whi + (size_t)idx * 8) = h;
    *(half8*)(wlo + (size_t)idx * 8) = l;
}

// ---------------- Main: coalesced-staged split-f16 MFMA GEMM + noise + bias + top-8 + softmax ----------------
// 512 thr = 8 waves = split-K x8. Tile 32 tokens x 64 experts. Grid 512 = 2 blocks/CU, 4 waves/SIMD.
// Staging: per K-window of 256 floats, each wave reads 4 FULL 1KB row segments (64 lanes x float4,
// perfectly contiguous -> m13-class HBM efficiency), converts to packed (hi f16 | lo f16 <<16) u32,
// ds_write_b128. Each wave then consumes its own 2 c16-chunks of the window (split-K).
__global__ __launch_bounds__(512, 4) void router_main(const float* __restrict__ x,
                                                      const f16_t* __restrict__ whi,
                                                      const f16_t* __restrict__ wlo,
                                                      const float* __restrict__ noise,
                                                      const float* __restrict__ ws_bias,
                                                      float* __restrict__ ws_batch,
                                                      float* __restrict__ out) {
    // 69,632 B: staging xtile 32 rows x 1040 B (33,280 B) overlaid by part[8][32][68] f32 afterwards
    __shared__ float smem[17408];
    __shared__ float bias_sh[64];
    __shared__ float loads_sh[64];

    const int tid = threadIdx.x;
    const int wv  = tid >> 6;        // 0..7: split-K partition (chunks s*16 + wv*2 + {0,1})
    const int L   = tid & 63;
    const int r   = L & 31;          // A-frag row (token within tile)
    const int kh  = L >> 5;
    const int token0 = blockIdx.x * 32;

    if (tid < 64) { bias_sh[tid] = ws_bias[tid]; loads_sh[tid] = 0.0f; }

    unsigned int* xt = (unsigned int*)smem;   // row stride 260 u32 = 1040 B (pad 16B: 2-way banks max)
    const half8* whi8 = (const half8*)whi;
    const half8* wlo8 = (const half8*)wlo;

    floatx16 acc0, acc1;
    #pragma unroll
    for (int i = 0; i < 16; ++i) { acc0[i] = 0.0f; acc1[i] = 0.0f; }

    for (int s = 0; s < 8; ++s) {
        __syncthreads();                       // previous window fully consumed
        #pragma unroll
        for (int q = 0; q < 4; ++q) {
            const int row = wv + q * 8;        // wave reads one whole 1KB row segment per q
            float4 v4 = *(const float4*)(x + (size_t)(token0 + row) * DIM + s * 256 + L * 4);
            uint4 p;
            {
                f16_t h0 = (f16_t)v4.x, h1 = (f16_t)v4.y, h2 = (f16_t)v4.z, h3 = (f16_t)v4.w;
                f16_t l0 = (f16_t)(v4.x - (float)h0), l1 = (f16_t)(v4.y - (float)h1);
                f16_t l2 = (f16_t)(v4.z - (float)h2), l3 = (f16_t)(v4.w - (float)h3);
                p.x = (unsigned int)__builtin_bit_cast(unsigned short, h0) |
                      ((unsigned int)__builtin_bit_cast(unsigned short, l0) << 16);
                p.y = (unsigned int)__builtin_bit_cast(unsigned short, h1) |
                      ((unsigned int)__builtin_bit_cast(unsigned short, l1) << 16);
                p.z = (unsigned int)__builtin_bit_cast(unsigned short, h2) |
                      ((unsigned int)__builtin_bit_cast(unsigned short, l2) << 16);
                p.w = (unsigned int)__builtin_bit_cast(unsigned short, h3) |
                      ((unsigned int)__builtin_bit_cast(unsigned short, l3) << 16);
            }
            *(uint4*)(xt + row * 260 + L * 4) = p;   // contiguous b128 write, conflict-free
        }
        __syncthreads();
        #pragma unroll
        for (int cc = 0; cc < 2; ++cc) {
            const int jw  = wv * 2 + cc;       // chunk within window
            const int c16 = s * 16 + jw;       // global 16-k chunk
            const unsigned int* fp = xt + r * 260 + jw * 16 + kh * 8;
            uint4 u0 = *(const uint4*)fp;      // 4 packed elems (hi|lo)
            uint4 u1 = *(const uint4*)(fp + 4);
            H8U4 ah, al;
            ah.u.x = (u0.x & 0xFFFFu) | (u0.y << 16);
            ah.u.y = (u0.z & 0xFFFFu) | (u0.w << 16);
            ah.u.z = (u1.x & 0xFFFFu) | (u1.y << 16);
            ah.u.w = (u1.z & 0xFFFFu) | (u1.w << 16);
            al.u.x = (u0.x >> 16) | (u0.y & 0xFFFF0000u);
            al.u.y = (u0.z >> 16) | (u0.w & 0xFFFF0000u);
            al.u.z = (u1.x >> 16) | (u1.y & 0xFFFF0000u);
            al.u.w = (u1.z >> 16) | (u1.w & 0xFFFF0000u);
            const int bidx = (c16 * 2) * 64 + L;
            half8 b0h = whi8[bidx];
            half8 b1h = whi8[bidx + 64];
            half8 b0l = wlo8[bidx];
            half8 b1l = wlo8[bidx + 64];
            acc0 = __builtin_amdgcn_mfma_f32_32x32x16_f16(ah.h, b0h, acc0, 0, 0, 0);
            acc1 = __builtin_amdgcn_mfma_f32_32x32x16_f16(ah.h, b1h, acc1, 0, 0, 0);
            acc0 = __builtin_amdgcn_mfma_f32_32x32x16_f16(al.h, b0h, acc0, 0, 0, 0);
            acc1 = __builtin_amdgcn_mfma_f32_32x32x16_f16(al.h, b1h, acc1, 0, 0, 0);
            acc0 = __builtin_amdgcn_mfma_f32_32x32x16_f16(ah.h, b0l, acc0, 0, 0, 0);
            acc1 = __builtin_amdgcn_mfma_f32_32x32x16_f16(ah.h, b1l, acc1, 0, 0, 0);
        }
    }

    __syncthreads();   // all frag reads done; reuse staging region as part[]

    // C/D layout (verified m74/m101 + R2/R3 pass): col=lane&31, row=(reg&3)+8*(reg>>2)+4*kh
    #pragma unroll
    for (int reg = 0; reg < 16; ++reg) {
        int row = (reg & 3) + 8 * (reg >> 2) + 4 * kh;
        smem[wv * 2176 + row * 68 + r]      = acc0[reg];
        smem[wv * 2176 + row * 68 + 32 + r] = acc1[reg];
    }
    __syncthreads();

    // Split-K reduce + noise + bias -> final logits into part[0]
    #pragma unroll
    for (int p = 0; p < 4; ++p) {
        int o = tid + p * 512;               // 0..2047
        int t = o >> 6, e = o & 63;
        float sum = 0.0f;
        #pragma unroll
        for (int q = 0; q < 8; ++q) sum += smem[q * 2176 + t * 68 + e];
        sum += noise[(size_t)(token0 + t) * NE + e] * 0.01f - bias_sh[e];
        smem[t * 68 + e] = sum;              // own slot; no cross-thread hazard
    }
    __syncthreads();

    // Top-8 (strict '>' keeps lower index on ties, matching jax.lax.top_k) + softmax + load scatter
    if (tid < 32) {
        int t = tid;
        float tv[TK]; int ti_[TK];
        #pragma unroll
        for (int j = 0; j < TK; ++j) { tv[j] = -INFINITY; ti_[j] = 0; }
        for (int e = 0; e < NE; ++e) {
            float v = smem[t * 68 + e]; int id = e;
            #pragma unroll
            for (int j = 0; j < TK; ++j) {
                bool gt = v > tv[j];
                float nv = gt ? v : tv[j];
                int   ni = gt ? id : ti_[j];
                float ov = gt ? tv[j] : v;
                int   oi = gt ? ti_[j] : id;
                tv[j] = nv; ti_[j] = ni; v = ov; id = oi;
            }
        }
        float m = tv[0], ssum = 0.0f, wvv[TK];
        #pragma unroll
        for (int j = 0; j < TK; ++j) { wvv[j] = expf(tv[j] - m); ssum += wvv[j]; }
        float inv = 1.0f / ssum;
        size_t gt_ = (size_t)(token0 + t);
        #pragma unroll
        for (int j = 0; j < TK; ++j) {
            float wgt = wvv[j] * inv;
            out[gt_ * TK + j] = (float)ti_[j];
            out[(size_t)NT * TK + gt_ * TK + j] = wgt;
            atomicAdd(&loads_sh[ti_[j]], wgt);
        }
    }
    __syncthreads();
    if (tid < 64) atomicAdd(&ws_batch[tid], loads_sh[tid]);
}

// ---------------- EMA load update ----------------
__global__ __launch_bounds__(64) void finalize_kernel(const float* __restrict__ expert_loads,
                                                      const float* __restrict__ ws_batch,
                                                      float* __restrict__ out_loads) {
    int e = threadIdx.x;
    out_loads[e] = 0.999f * expert_loads[e] + 0.001f * (ws_batch[e] / (float)NT);
}

extern "C" void kernel_launch(void* const* d_in, const int* in_sizes, int n_in,
                              void* d_out, int out_size, void* d_ws, size_t ws_size,
                              hipStream_t stream) {
    const float* x     = (const float*)d_in[0];  // [16384, 2048]
    const float* rw    = (const float*)d_in[1];  // [64, 2048]
    const float* loads = (const float*)d_in[2];  // [64]
    const float* bs    = (const float*)d_in[3];  // [1]
    const float* noise = (const float*)d_in[4];  // [16384, 64]
    float* out = (float*)d_out;                  // [131072 idx | 131072 w | 64 loads | 1 bias]
    float* ws  = (float*)d_ws;
    float* ws_bias  = ws;
    float* ws_batch = ws + 64;
    f16_t* whi = (f16_t*)(ws + 128);             // 16384 frags x 8 halves = 256 KB
    f16_t* wlo = whi + (size_t)16384 * 8;        // another 256 KB

    prep_kernel<<<65, 256, 0, stream>>>(rw, loads, bs, ws_bias, ws_batch, whi, wlo,
                                        out + (size_t)NT * TK * 2 + NE);
    router_main<<<NT / 32, 512, 0, stream>>>(x, whi, wlo, noise, ws_bias, ws_batch, out);
    finalize_kernel<<<1, 64, 0, stream>>>(loads, ws_batch, out + (size_t)NT * TK * 2);
}